// Round 9
// baseline (513.430 us; speedup 1.0000x reference)
//
#include <hip/hip_runtime.h>
#include <hip/hip_bf16.h>

#define SHIFT 4

typedef short bf16x8 __attribute__((ext_vector_type(8)));
typedef float f32x4  __attribute__((ext_vector_type(4)));

#define MFMA(a, b, c) __builtin_amdgcn_mfma_f32_16x16x32_bf16((a), (b), (c), 0, 0, 0)

__device__ __forceinline__ unsigned short f2bf(float f) {
  __hip_bfloat16 h = __float2bfloat16(f);   // RNE, HW cvt_pk on gfx950
  return __hip_bfloat16_raw(h).x;
}
__device__ __forceinline__ float bf2f(unsigned short u) {
  return __uint_as_float(((unsigned int)u) << 16);
}

// ---------------------------------------------------------------------------
// Kernel 0a: fp32 -> bf16 weight conversion (linear)
// ---------------------------------------------------------------------------
__global__ void k_cvt(const float* __restrict__ s, unsigned short* __restrict__ d, int n) {
  int i = blockIdx.x * blockDim.x + threadIdx.x;
  int st = gridDim.x * blockDim.x;
  for (; i < n; i += st) d[i] = f2bf(s[i]);
}

// ---------------------------------------------------------------------------
// Kernel 0b: fp32 -> bf16 + permute w1 [384][96] -> [24cb][3ks][16][32] tiles
// ---------------------------------------------------------------------------
__global__ void k_cvt_p1(const float* __restrict__ s, unsigned short* __restrict__ d) {
  int i = blockIdx.x * 256 + threadIdx.x;
  if (i < 36864) {
    int col = i / 96, k = i - col * 96;
    d[(((col >> 4) * 3 + (k >> 5)) << 9) + ((col & 15) << 5) + (k & 31)] = f2bf(s[i]);
  }
}
// w2 [96][384] -> [6cb][12ks][16][32]
__global__ void k_cvt_p2(const float* __restrict__ s, unsigned short* __restrict__ d) {
  int i = blockIdx.x * 256 + threadIdx.x;
  if (i < 36864) {
    int col = i / 384, k = i - col * 384;
    d[(((col >> 4) * 12 + (k >> 5)) << 9) + ((col & 15) << 5) + (k & 31)] = f2bf(s[i]);
  }
}

// ---------------------------------------------------------------------------
// Kernel 0c: planar fp32 [96][512][512] -> token-major bf16 X[tok][96]
// ---------------------------------------------------------------------------
__global__ __launch_bounds__(256, 8) void k_pre(
    const float* __restrict__ x, unsigned short* __restrict__ X)
{
  __shared__ __align__(16) unsigned short xls[64 * 104];
  const int tid = threadIdx.x;
  const int bid = blockIdx.x;
  const int b  = bid >> 12;
  const int h  = (bid >> 3) & 511;
  const int w0 = (bid & 7) << 6;

#pragma unroll
  for (int v = 0; v < 6; ++v) {
    int idx4 = v * 256 + tid;       // 0..1535
    int c    = idx4 >> 4;           // channel 0..95
    int p4   = (idx4 & 15) << 2;    // pixel group
    const float4 f = *reinterpret_cast<const float4*>(
        &x[((size_t)(b * 96 + c) << 18) + (h << 9) + w0 + p4]);
    xls[(p4 + 0) * 104 + c] = f2bf(f.x);
    xls[(p4 + 1) * 104 + c] = f2bf(f.y);
    xls[(p4 + 2) * 104 + c] = f2bf(f.z);
    xls[(p4 + 3) * 104 + c] = f2bf(f.w);
  }
  __syncthreads();
  const int q = tid & 3, t = tid >> 2;
  unsigned short* Xo = &X[(size_t)((b << 18) + (h << 9) + w0 + t) * 96 + q * 24];
#pragma unroll
  for (int v = 0; v < 3; ++v)
    *reinterpret_cast<bf16x8*>(&Xo[v * 8]) =
        *reinterpret_cast<const bf16x8*>(&xls[t * 104 + q * 24 + v * 8]);
}

// ---------------------------------------------------------------------------
// Kernel 1: per-window  LN1 + QKV + attention + proj + shortcut, IN-PLACE on X
// All weight B-frags hoisted in 9-frag batches (one waitcnt per batch, not
// per MFMA).  Epilogue stays in frag layout: xv registers carry the residual,
// X is stored at the same addresses the frag-load read (wave-private band).
// grid = 8192, block = 256 (4 waves). 1 barrier. LDS 40448 -> 4 blocks/CU.
// ---------------------------------------------------------------------------
__global__ __launch_bounds__(256, 4) void k_attn(
    const float* __restrict__ ln1g, const float* __restrict__ ln1b,
    const unsigned short* __restrict__ qkvw,   // bf16 [288][96]
    const float* __restrict__ qkvb,
    const float* __restrict__ lapA, const float* __restrict__ lapB,
    const unsigned short* __restrict__ projw,  // bf16 [96][96]
    const float* __restrict__ projb,
    unsigned short* __restrict__ X)            // bf16 [2*512*512][96], in-place
{
  // R1 multiplexes (stride 104, rows wave-band-private): Q -> P -> O -> proj
  __shared__ __align__(16) unsigned short R1[64 * 104];
  __shared__ __align__(16) unsigned short Ks[64 * 104];
  __shared__ __align__(16) unsigned short Vt[96 * 72];   // V^T [d][key(+pad)]

  const int tid = threadIdx.x;
  const int wid = blockIdx.x;
  const int b   = wid >> 12;
  const int hi  = (wid >> 6) & 63;
  const int wi  = wid & 63;
  const int lane = tid & 63;
  const int wv   = tid >> 6;
  const int l16  = lane & 15;
  const int lg   = lane >> 4;
  const int arow = wv * 16 + l16;
  const f32x4 zz = {0.f, 0.f, 0.f, 0.f};

  const int sh = ((hi & 1) == 0) ? -SHIFT : SHIFT;   // gather source offset

  // ---- direct frag-layout load: lane holds token (wv*16+l16), k = ks*32+lg*8 ----
  const int ftok = wv * 16 + l16;
  const int fhh = hi * 8 + (ftok >> 3);
  const int fww = ((wi * 8 + (ftok & 7)) + sh) & 511;
  unsigned short* xfp = &X[(size_t)((b << 18) + (fhh << 9) + fww) * 96 + lg * 8];

  float xv[24];                                 // stays live: residual source
#pragma unroll
  for (int ks = 0; ks < 3; ++ks) {
    bf16x8 g = *reinterpret_cast<const bf16x8*>(&xfp[ks * 32]);
#pragma unroll
    for (int e = 0; e < 8; ++e) xv[ks * 8 + e] = bf2f((unsigned short)g[e]);
  }
  // ---- LN1 stats: lanes l, l^16, l^32 hold the same token ----
  float mu, rs;
  {
    float s1 = 0.f, s2 = 0.f;
#pragma unroll
    for (int k = 0; k < 24; ++k) { float v = xv[k]; s1 += v; s2 += v * v; }
    s1 += __shfl_xor(s1, 16); s2 += __shfl_xor(s2, 16);
    s1 += __shfl_xor(s1, 32); s2 += __shfl_xor(s2, 32);
    mu = s1 * (1.f / 96.f);
    rs = rsqrtf(s2 * (1.f / 96.f) - mu * mu + 1e-5f);
  }
  // ---- A-frags in registers, no LDS ----
  bf16x8 afr[3];
#pragma unroll
  for (int ks = 0; ks < 3; ++ks) {
#pragma unroll
    for (int e = 0; e < 8; ++e) {
      int c = ks * 32 + lg * 8 + e;
      afr[ks][e] = (short)f2bf((xv[ks * 8 + e] - mu) * rs * ln1g[c] + ln1b[c]);
    }
  }

  const float qscale = 0.17677669529663687f;  // 32^-0.5
  // ---- QKV GEMM, B-frags hoisted 9 at a time ----
  // Q -> R1 (band-private)
#pragma unroll
  for (int half = 0; half < 2; ++half) {
    bf16x8 wf[9];
#pragma unroll
    for (int i = 0; i < 9; ++i) {
      int col = (half * 3 + i / 3) * 16 + l16;
      wf[i] = *reinterpret_cast<const bf16x8*>(&qkvw[col * 96 + (i % 3) * 32 + lg * 8]);
    }
#pragma unroll
    for (int ntl = 0; ntl < 3; ++ntl) {
      int col = (half * 3 + ntl) * 16 + l16;
      f32x4 acc = zz;
#pragma unroll
      for (int ks = 0; ks < 3; ++ks) acc = MFMA(afr[ks], wf[ntl * 3 + ks], acc);
      float bc = qkvb[col];
#pragma unroll
      for (int j = 0; j < 4; ++j)
        R1[(wv * 16 + lg * 4 + j) * 104 + col] = f2bf((acc[j] + bc) * qscale);
    }
  }
  // K -> Ks
#pragma unroll
  for (int half = 0; half < 2; ++half) {
    bf16x8 wf[9];
#pragma unroll
    for (int i = 0; i < 9; ++i) {
      int col = 96 + (half * 3 + i / 3) * 16 + l16;
      wf[i] = *reinterpret_cast<const bf16x8*>(&qkvw[col * 96 + (i % 3) * 32 + lg * 8]);
    }
#pragma unroll
    for (int ntl = 0; ntl < 3; ++ntl) {
      int nt = half * 3 + ntl;
      int col = 96 + nt * 16 + l16;
      f32x4 acc = zz;
#pragma unroll
      for (int ks = 0; ks < 3; ++ks) acc = MFMA(afr[ks], wf[ntl * 3 + ks], acc);
      float bc = qkvb[col];
#pragma unroll
      for (int j = 0; j < 4; ++j)
        Ks[(wv * 16 + lg * 4 + j) * 104 + nt * 16 + l16] = f2bf(acc[j] + bc);
    }
  }
  // V -> Vt (transposed)
#pragma unroll
  for (int half = 0; half < 2; ++half) {
    bf16x8 wf[9];
#pragma unroll
    for (int i = 0; i < 9; ++i) {
      int col = 192 + (half * 3 + i / 3) * 16 + l16;
      wf[i] = *reinterpret_cast<const bf16x8*>(&qkvw[col * 96 + (i % 3) * 32 + lg * 8]);
    }
#pragma unroll
    for (int ntl = 0; ntl < 3; ++ntl) {
      int nt = half * 3 + ntl;
      int col = 192 + nt * 16 + l16;
      f32x4 acc = zz;
#pragma unroll
      for (int ks = 0; ks < 3; ++ks) acc = MFMA(afr[ks], wf[ntl * 3 + ks], acc);
      float bc = qkvb[col];
#pragma unroll
      for (int j = 0; j < 4; ++j)
        Vt[(nt * 16 + l16) * 72 + wv * 16 + lg * 4 + j] = f2bf(acc[j] + bc);
    }
  }

  // ---- Laplacian bias in registers (before barrier: off the critical path) ----
  float bias_r[4][4];
  {
    const float a = lapA[0], bb = lapB[0];
    const float A2 = a * a;
    const float nh = -0.5f / (bb * bb);
#pragma unroll
    for (int j = 0; j < 4; ++j) {
      int qi = wv * 16 + lg * 4 + j;
      int qr = qi >> 3, qc = qi & 7;
#pragma unroll
      for (int kt = 0; kt < 4; ++kt) {
        int key = kt * 16 + l16;
        int dd = abs(qr - (key >> 3)) + abs(qc - (key & 7));
        bias_r[j][kt] = A2 * __expf(nh * (float)dd);
      }
    }
  }
  __syncthreads();   // the ONE barrier: Ks/Vt read cross-wave

  bf16x8 aqh[3];
#pragma unroll
  for (int h = 0; h < 3; ++h)
    aqh[h] = *reinterpret_cast<const bf16x8*>(&R1[arow * 104 + h * 32 + lg * 8]);

  f32x4 oacc[6];
#pragma unroll
  for (int i = 0; i < 6; ++i) oacc[i] = zz;

#pragma unroll 1
  for (int h = 0; h < 3; ++h) {
    f32x4 sc[4];
#pragma unroll
    for (int kt = 0; kt < 4; ++kt) {
      bf16x8 bk = *reinterpret_cast<const bf16x8*>(&Ks[(kt * 16 + l16) * 104 + h * 32 + lg * 8]);
      sc[kt] = MFMA(aqh[h], bk, zz);
    }
    // softmax over 64 keys (no max-subtract: scores bounded, fp32 exp safe)
#pragma unroll
    for (int j = 0; j < 4; ++j) {
      int qi = wv * 16 + lg * 4 + j;
      float e0 = __expf(sc[0][j] + bias_r[j][0]);
      float e1 = __expf(sc[1][j] + bias_r[j][1]);
      float e2 = __expf(sc[2][j] + bias_r[j][2]);
      float e3 = __expf(sc[3][j] + bias_r[j][3]);
      float s = e0 + e1 + e2 + e3;
#pragma unroll
      for (int off = 1; off < 16; off <<= 1) s += __shfl_xor(s, off);
      float inv = 1.0f / s;
      R1[qi * 104 +  0 + l16] = f2bf(e0 * inv);
      R1[qi * 104 + 16 + l16] = f2bf(e1 * inv);
      R1[qi * 104 + 32 + l16] = f2bf(e2 * inv);
      R1[qi * 104 + 48 + l16] = f2bf(e3 * inv);
    }
    // PV (P band is wave-private)
    bf16x8 ap0 = *reinterpret_cast<const bf16x8*>(&R1[arow * 104 +  0 + lg * 8]);
    bf16x8 ap1 = *reinterpret_cast<const bf16x8*>(&R1[arow * 104 + 32 + lg * 8]);
#pragma unroll
    for (int dt = 0; dt < 2; ++dt) {
      int vcol = h * 32 + dt * 16 + l16;
      bf16x8 bv0 = *reinterpret_cast<const bf16x8*>(&Vt[vcol * 72 +  0 + lg * 8]);
      bf16x8 bv1 = *reinterpret_cast<const bf16x8*>(&Vt[vcol * 72 + 32 + lg * 8]);
      oacc[h * 2 + dt] = MFMA(ap0, bv0, oacc[h * 2 + dt]);
      oacc[h * 2 + dt] = MFMA(ap1, bv1, oacc[h * 2 + dt]);
    }
  }
  // O -> R1 (tramples P; band-private)
#pragma unroll
  for (int i = 0; i < 6; ++i)
#pragma unroll
    for (int j = 0; j < 4; ++j)
      R1[(wv * 16 + lg * 4 + j) * 104 + i * 16 + l16] = f2bf(oacc[i][j]);

  // ---- proj -> R1 band (C-layout, band-private), B-frags hoisted ----
  bf16x8 ao[3];
#pragma unroll
  for (int ks = 0; ks < 3; ++ks)
    ao[ks] = *reinterpret_cast<const bf16x8*>(&R1[arow * 104 + ks * 32 + lg * 8]);
#pragma unroll
  for (int half = 0; half < 2; ++half) {
    bf16x8 wf[9];
#pragma unroll
    for (int i = 0; i < 9; ++i) {
      int col = (half * 3 + i / 3) * 16 + l16;
      wf[i] = *reinterpret_cast<const bf16x8*>(&projw[col * 96 + (i % 3) * 32 + lg * 8]);
    }
#pragma unroll
    for (int ntl = 0; ntl < 3; ++ntl) {
      int col = (half * 3 + ntl) * 16 + l16;
      f32x4 acc = zz;
#pragma unroll
      for (int ks = 0; ks < 3; ++ks) acc = MFMA(ao[ks], wf[ntl * 3 + ks], acc);
      float pb = projb[col];
#pragma unroll
      for (int j = 0; j < 4; ++j)
        R1[(wv * 16 + lg * 4 + j) * 104 + col] = f2bf(acc[j] + pb);
    }
  }
  // ---- epilogue in FRAG layout: own band row, xv residual, store to xfp ----
#pragma unroll
  for (int ks = 0; ks < 3; ++ks) {
    bf16x8 m = *reinterpret_cast<const bf16x8*>(&R1[ftok * 104 + ks * 32 + lg * 8]);
    bf16x8 pk;
#pragma unroll
    for (int e = 0; e < 8; ++e)
      pk[e] = (short)f2bf(bf2f((unsigned short)m[e]) + xv[ks * 8 + e]);
    *reinterpret_cast<bf16x8*>(&xfp[ks * 32]) = pk;
  }
}

// ---------------------------------------------------------------------------
// Kernel 2: weight-stationary MLP.
//   512 threads (8 waves = 2/SIMD), 128-token strips, 0 in-loop barriers.
//   LDS: w1 (73728) + w2 tiles 0-67 (69632) + Hl[128][72] (18432) = 161792 B.
//   w2 tiles 68-71 in register B-frags.  A-frags direct from X (frag layout).
//   grid = 512, 8 strips per block.
// ---------------------------------------------------------------------------
__global__ __launch_bounds__(512, 2) void k_mlp(
    const unsigned short* __restrict__ X,      // bf16 [2*512*512][96] (= xt)
    const float* __restrict__ ln2g, const float* __restrict__ ln2b,
    const unsigned short* __restrict__ w1p,    // bf16 permuted [24cb][3ks][16][32]
    const float* __restrict__ b1,
    const unsigned short* __restrict__ w2p,    // bf16 permuted [6cb][12ks][16][32]
    const float* __restrict__ b2,
    float* __restrict__ out)
{
  __shared__ __align__(16) unsigned short Wl[36864];     // w1, 73728 B
  __shared__ __align__(16) unsigned short W2l[34816];    // w2 tiles 0-67, 69632 B
  __shared__ __align__(16) unsigned short Hl[128 * 72];  // 18432 B (Hl chunk / out stage)

  const int tid = threadIdx.x;
  const int q    = tid & 3;
  const int t    = tid >> 2;      // owned token 0..127
  const int lane = tid & 63;
  const int wv   = tid >> 6;      // 0..7
  const int l16  = lane & 15;
  const int lg   = lane >> 4;
  const f32x4 zz = {0.f, 0.f, 0.f, 0.f};

  // ---- stage weights into LDS ----
#pragma unroll
  for (int it = 0; it < 9; ++it) {
    int v8 = it * 512 + tid;
    *reinterpret_cast<bf16x8*>(&Wl[v8 * 8]) = *reinterpret_cast<const bf16x8*>(&w1p[v8 * 8]);
    if (v8 < 4352)
      *reinterpret_cast<bf16x8*>(&W2l[v8 * 8]) = *reinterpret_cast<const bf16x8*>(&w2p[v8 * 8]);
  }
  // w2 tiles 68..71 as register B-frags
  bf16x8 wfr[4];
#pragma unroll
  for (int r = 0; r < 4; ++r)
    wfr[r] = *reinterpret_cast<const bf16x8*>(&w2p[((68 + r) << 9) + (l16 << 5) + lg * 8]);

  // ---- loop-invariant preloads ----
  float gr[24], br[24], b1r[24], b2r[6];
#pragma unroll
  for (int i = 0; i < 24; ++i) {
    int c = (i >> 3) * 32 + lg * 8 + (i & 7);
    gr[i] = ln2g[c]; br[i] = ln2b[c];
  }
#pragma unroll
  for (int i = 0; i < 24; ++i) b1r[i] = b1[i * 16 + l16];
#pragma unroll
  for (int i = 0; i < 6; ++i) b2r[i] = b2[i * 16 + l16];

  __syncthreads();   // weights staged (the only barrier)

#pragma unroll 1
  for (int s = 0; s < 8; ++s) {
    const int stb = (blockIdx.x * 8 + s) * 128;   // strip token base

    // ---- direct frag-layout load + LN2 (no LDS) ----
    const unsigned short* xfp = &X[(size_t)(stb + wv * 16 + l16) * 96 + lg * 8];
    float xv[24];
#pragma unroll
    for (int ks = 0; ks < 3; ++ks) {
      bf16x8 g = *reinterpret_cast<const bf16x8*>(&xfp[ks * 32]);
#pragma unroll
      for (int e = 0; e < 8; ++e) xv[ks * 8 + e] = bf2f((unsigned short)g[e]);
    }
    float mu, rs;
    {
      float s1 = 0.f, s2 = 0.f;
#pragma unroll
      for (int k = 0; k < 24; ++k) { float v = xv[k]; s1 += v; s2 += v * v; }
      s1 += __shfl_xor(s1, 16); s2 += __shfl_xor(s2, 16);
      s1 += __shfl_xor(s1, 32); s2 += __shfl_xor(s2, 32);
      mu = s1 * (1.f / 96.f);
      rs = rsqrtf(s2 * (1.f / 96.f) - mu * mu + 1e-5f);
    }
    bf16x8 a1[3];
#pragma unroll
    for (int ks = 0; ks < 3; ++ks)
#pragma unroll
      for (int e = 0; e < 8; ++e)
        a1[ks][e] = (short)f2bf((xv[ks * 8 + e] - mu) * rs * gr[ks * 8 + e] + br[ks * 8 + e]);

    f32x4 acc2[6];
#pragma unroll
    for (int i = 0; i < 6; ++i) acc2[i] = zz;

    // ---- hidden in 6 chunks of 64: GEMM1+GELU -> Hl -> GEMM2 accumulate ----
#pragma unroll
    for (int ch = 0; ch < 6; ++ch) {
#pragma unroll
      for (int nt = 0; nt < 4; ++nt) {
        const int ntg = ch * 4 + nt;
        f32x4 acc = zz;
#pragma unroll
        for (int ks = 0; ks < 3; ++ks)
          acc = MFMA(a1[ks],
                     *reinterpret_cast<const bf16x8*>(&Wl[((ntg * 3 + ks) << 9) + (l16 << 5) + lg * 8]),
                     acc);
        float bb = b1r[ntg];
#pragma unroll
        for (int j = 0; j < 4; ++j) {
          float v = acc[j] + bb;
          // gelu(v) ~= v * sigmoid(1.5957691 v + 0.071354816 v^3)
          float tt = v * fmaf(0.071354816f, v * v, 1.5957691f);
          float g = v * __builtin_amdgcn_rcpf(1.f + __expf(-tt));
          Hl[(wv * 16 + lg * 4 + j) * 72 + nt * 16 + l16] = f2bf(g);
        }
      }
      bf16x8 ah0 = *reinterpret_cast<const bf16x8*>(&Hl[(wv * 16 + l16) * 72 + lg * 8]);
      bf16x8 ah1 = *reinterpret_cast<const bf16x8*>(&Hl[(wv * 16 + l16) * 72 + 32 + lg * 8]);
#pragma unroll
      for (int nt = 0; nt < 6; ++nt) {
        const int t0 = nt * 12 + ch * 2;
        const int t1 = t0 + 1;
        bf16x8 bf0 = (t0 >= 68) ? wfr[(t0 - 68) & 3]
                   : *reinterpret_cast<const bf16x8*>(&W2l[(t0 << 9) + (l16 << 5) + lg * 8]);
        bf16x8 bf1 = (t1 >= 68) ? wfr[(t1 - 68) & 3]
                   : *reinterpret_cast<const bf16x8*>(&W2l[(t1 << 9) + (l16 << 5) + lg * 8]);
        acc2[nt] = MFMA(ah0, bf0, acc2[nt]);
        acc2[nt] = MFMA(ah1, bf1, acc2[nt]);
      }
    }

    // ---- epilogue: 2-pass stage via Hl, residual re-read, planar fp32 store ----
    const int tok = stb + t;
    const unsigned short* xrp = &X[(size_t)tok * 96 + q * 24];
    const int bb_ = tok >> 18;
    const int pix = tok & 262143;
#pragma unroll
    for (int pass = 0; pass < 2; ++pass) {
      // stage output cols 48*pass .. 48*pass+47 (band-private)
#pragma unroll
      for (int ntl = 0; ntl < 3; ++ntl) {
        const int nt = pass * 3 + ntl;
#pragma unroll
        for (int j = 0; j < 4; ++j)
          Hl[(wv * 16 + lg * 4 + j) * 72 + ntl * 16 + l16] = f2bf(acc2[nt][j] + b2r[nt]);
      }
      if ((q >> 1) == pass) {
        const int lc = (q & 1) * 24;
#pragma unroll
        for (int v = 0; v < 3; ++v) {
          bf16x8 m  = *reinterpret_cast<const bf16x8*>(&Hl[t * 72 + lc + v * 8]);
          bf16x8 xr = *reinterpret_cast<const bf16x8*>(&xrp[v * 8]);
#pragma unroll
          for (int e = 0; e < 8; ++e) {
            int c = q * 24 + v * 8 + e;
            out[((size_t)(bb_ * 96 + c) << 18) + pix] =
                bf2f((unsigned short)m[e]) + bf2f((unsigned short)xr[e]);
          }
        }
      }
    }
  }
}

// ---------------------------------------------------------------------------
extern "C" void kernel_launch(void* const* d_in, const int* in_sizes, int n_in,
                              void* d_out, int out_size, void* d_ws, size_t ws_size,
                              hipStream_t stream) {
  const float* x     = (const float*)d_in[0];
  const float* ln1g  = (const float*)d_in[1];
  const float* ln1b  = (const float*)d_in[2];
  const float* qkv_w = (const float*)d_in[3];
  const float* qkv_b = (const float*)d_in[4];
  const float* lapA  = (const float*)d_in[5];
  const float* lapB  = (const float*)d_in[6];
  const float* prj_w = (const float*)d_in[7];
  const float* prj_b = (const float*)d_in[8];
  const float* ln2g  = (const float*)d_in[9];
  const float* ln2b  = (const float*)d_in[10];
  const float* w1f   = (const float*)d_in[11];
  const float* b1    = (const float*)d_in[12];
  const float* w2f   = (const float*)d_in[13];
  const float* b2    = (const float*)d_in[14];

  char* ws = (char*)d_ws;
  unsigned short* X     = (unsigned short*)ws;                 // bf16 [524288][96], in-place x -> xt
  unsigned short* qkvwb = (unsigned short*)(ws + 100663296);
  unsigned short* prjwb = (unsigned short*)(ws + 100718592);
  unsigned short* w1p   = (unsigned short*)(ws + 100737024);   // permuted tiles
  unsigned short* w2p   = (unsigned short*)(ws + 100810752);   // permuted tiles

  k_cvt   <<<64, 256, 0, stream>>>(qkv_w, qkvwb, 288 * 96);
  k_cvt   <<<64, 256, 0, stream>>>(prj_w, prjwb, 96 * 96);
  k_cvt_p1<<<144, 256, 0, stream>>>(w1f, w1p);
  k_cvt_p2<<<144, 256, 0, stream>>>(w2f, w2p);

  k_pre <<<8192, 256, 0, stream>>>(x, X);
  k_attn<<<8192, 256, 0, stream>>>(ln1g, ln1b, qkvwb, qkv_b, lapA, lapB,
                                   prjwb, prj_b, X);
  k_mlp <<<512, 512, 0, stream>>>(X, ln2g, ln2b, w1p, b1, w2p, b2,
                                  (float*)d_out);
}

// Round 10
// 467.355 us; speedup vs baseline: 1.0986x; 1.0986x over previous
//
#include <hip/hip_runtime.h>
#include <hip/hip_bf16.h>

#define SHIFT 4

typedef short bf16x8 __attribute__((ext_vector_type(8)));
typedef float f32x4  __attribute__((ext_vector_type(4)));

#define MFMA(a, b, c) __builtin_amdgcn_mfma_f32_16x16x32_bf16((a), (b), (c), 0, 0, 0)

__device__ __forceinline__ unsigned short f2bf(float f) {
  __hip_bfloat16 h = __float2bfloat16(f);   // RNE
  return __hip_bfloat16_raw(h).x;
}
__device__ __forceinline__ float bf2f(unsigned short u) {
  return __uint_as_float(((unsigned int)u) << 16);
}

// ---------------------------------------------------------------------------
// Kernel 0a: fp32 [N][96] -> bf16 permuted [cb][3ks][16][32] tiles
// ---------------------------------------------------------------------------
__global__ void k_cvt_pt(const float* __restrict__ s, unsigned short* __restrict__ d, int n) {
  int i = blockIdx.x * 256 + threadIdx.x;
  if (i < n) {
    int col = i / 96, k = i - col * 96;
    d[(((col >> 4) * 3 + (k >> 5)) << 9) + ((col & 15) << 5) + (k & 31)] = f2bf(s[i]);
  }
}
// w2 [96][384] -> [6cb][12ks][16][32]
__global__ void k_cvt_p2(const float* __restrict__ s, unsigned short* __restrict__ d) {
  int i = blockIdx.x * 256 + threadIdx.x;
  if (i < 36864) {
    int col = i / 384, k = i - col * 384;
    d[(((col >> 4) * 12 + (k >> 5)) << 9) + ((col & 15) << 5) + (k & 31)] = f2bf(s[i]);
  }
}

// ---------------------------------------------------------------------------
// Kernel 0c: planar fp32 [96][512][512] -> token-major bf16 X[tok][96]
// ---------------------------------------------------------------------------
__global__ __launch_bounds__(256, 8) void k_pre(
    const float* __restrict__ x, unsigned short* __restrict__ X)
{
  __shared__ __align__(16) unsigned short xls[64 * 104];
  const int tid = threadIdx.x;
  const int bid = blockIdx.x;
  const int b  = bid >> 12;
  const int h  = (bid >> 3) & 511;
  const int w0 = (bid & 7) << 6;

#pragma unroll
  for (int v = 0; v < 6; ++v) {
    int idx4 = v * 256 + tid;
    int c    = idx4 >> 4;
    int p4   = (idx4 & 15) << 2;
    const float4 f = *reinterpret_cast<const float4*>(
        &x[((size_t)(b * 96 + c) << 18) + (h << 9) + w0 + p4]);
    xls[(p4 + 0) * 104 + c] = f2bf(f.x);
    xls[(p4 + 1) * 104 + c] = f2bf(f.y);
    xls[(p4 + 2) * 104 + c] = f2bf(f.z);
    xls[(p4 + 3) * 104 + c] = f2bf(f.w);
  }
  __syncthreads();
  const int q = tid & 3, t = tid >> 2;
  unsigned short* Xo = &X[(size_t)((b << 18) + (h << 9) + w0 + t) * 96 + q * 24];
#pragma unroll
  for (int v = 0; v < 3; ++v)
    *reinterpret_cast<bf16x8*>(&Xo[v * 8]) =
        *reinterpret_cast<const bf16x8*>(&xls[t * 104 + q * 24 + v * 8]);
}

// ---------------------------------------------------------------------------
// Kernel 1: weight-stationary windowed attention, IN-PLACE on X.
//   grid 256 x 512 thr (8 waves = 2/SIMD).  qkv+proj weights staged once in
//   LDS (permuted conflict-free tiles).  2 windows concurrent (one per 4-wave
//   group), 16 iterations = 32 windows/block.  Cross-window X prefetch.
//   LDS = 73728 (W) + 2*40448 (R1/Ks/Vt per group) = 154624 B -> 1 block/CU.
// ---------------------------------------------------------------------------
__global__ __launch_bounds__(512, 1) void k_attn(
    const float* __restrict__ ln1g, const float* __restrict__ ln1b,
    const unsigned short* __restrict__ qkvwp,  // bf16 permuted [18cb][3ks][16][32]
    const float* __restrict__ qkvb,
    const float* __restrict__ lapA, const float* __restrict__ lapB,
    const unsigned short* __restrict__ projwp, // bf16 permuted [6cb][3ks][16][32]
    const float* __restrict__ projb,
    unsigned short* __restrict__ X)            // bf16 [2*512*512][96], in-place
{
  __shared__ __align__(16) unsigned short WqkvL[27648];   // 55296 B
  __shared__ __align__(16) unsigned short WprojL[9216];   // 18432 B
  __shared__ __align__(16) unsigned short R1s[2][6656];   // [64][104] per group
  __shared__ __align__(16) unsigned short Kss[2][6656];   // [64][104] per group
  __shared__ __align__(16) unsigned short Vts[2][6912];   // [96][72]  per group

  const int tid  = threadIdx.x;
  const int lane = tid & 63;
  const int wv8  = tid >> 6;       // 0..7
  const int g    = wv8 >> 2;       // window group 0/1
  const int wvg  = wv8 & 3;        // wave within group
  const int l16  = lane & 15;
  const int lg   = lane >> 4;
  const int arow = wvg * 16 + l16;
  const f32x4 zz = {0.f, 0.f, 0.f, 0.f};

  unsigned short* R1 = R1s[g];
  unsigned short* Ks = Kss[g];
  unsigned short* Vt = Vts[g];

  // ---- stage weights into LDS (once) ----
#pragma unroll
  for (int it = 0; it < 7; ++it) {
    int v8 = it * 512 + tid;
    if (v8 < 3456)
      *reinterpret_cast<bf16x8*>(&WqkvL[v8 * 8]) =
          *reinterpret_cast<const bf16x8*>(&qkvwp[v8 * 8]);
  }
#pragma unroll
  for (int it = 0; it < 3; ++it) {
    int v8 = it * 512 + tid;
    if (v8 < 1152)
      *reinterpret_cast<bf16x8*>(&WprojL[v8 * 8]) =
          *reinterpret_cast<const bf16x8*>(&projwp[v8 * 8]);
  }

  // ---- loop-invariant preloads ----
  float gl[24], bl[24];
#pragma unroll
  for (int i = 0; i < 24; ++i) {
    int c = (i >> 3) * 32 + lg * 8 + (i & 7);
    gl[i] = ln1g[c]; bl[i] = ln1b[c];
  }
  float qb[18];
#pragma unroll
  for (int nt = 0; nt < 18; ++nt) qb[nt] = qkvb[nt * 16 + l16];
  float pbr[6];
#pragma unroll
  for (int nt = 0; nt < 6; ++nt) pbr[nt] = projb[nt * 16 + l16];

  float bias_r[4][4];
  {
    const float a = lapA[0], bb = lapB[0];
    const float A2 = a * a;
    const float nh = -0.5f / (bb * bb);
#pragma unroll
    for (int j = 0; j < 4; ++j) {
      int qi = wvg * 16 + lg * 4 + j;
      int qr = qi >> 3, qc = qi & 7;
#pragma unroll
      for (int kt = 0; kt < 4; ++kt) {
        int key = kt * 16 + l16;
        int dd = abs(qr - (key >> 3)) + abs(qc - (key & 7));
        bias_r[j][kt] = A2 * __expf(nh * (float)dd);
      }
    }
  }
  __syncthreads();   // weights staged

  const float qscale = 0.17677669529663687f;  // 32^-0.5
  const int ftok = wvg * 16 + l16;

  // frag-layout X address for window w (this lane's token row, k-offset lg*8)
  auto xaddr = [&](int w) -> unsigned short* {
    int b  = w >> 12;
    int hi = (w >> 6) & 63;
    int wi = w & 63;
    int sh = ((hi & 1) == 0) ? -SHIFT : SHIFT;
    int fhh = hi * 8 + (ftok >> 3);
    int fww = ((wi * 8 + (ftok & 7)) + sh) & 511;
    return &X[(size_t)((b << 18) + (fhh << 9) + fww) * 96 + lg * 8];
  };

  int w = blockIdx.x * 32 + g;
  unsigned short* xfp = xaddr(w);
  bf16x8 xn[3];
#pragma unroll
  for (int ks = 0; ks < 3; ++ks)
    xn[ks] = *reinterpret_cast<const bf16x8*>(&xfp[ks * 32]);

#pragma unroll 1
  for (int it = 0; it < 16; ++it) {
    // ---- convert prefetched X; LN1 via shfl(16/32) ----
    float xv[24];
#pragma unroll
    for (int ks = 0; ks < 3; ++ks)
#pragma unroll
      for (int e = 0; e < 8; ++e) xv[ks * 8 + e] = bf2f((unsigned short)xn[ks][e]);

    float mu, rs;
    {
      float s1 = 0.f, s2 = 0.f;
#pragma unroll
      for (int k = 0; k < 24; ++k) { float v = xv[k]; s1 += v; s2 += v * v; }
      s1 += __shfl_xor(s1, 16); s2 += __shfl_xor(s2, 16);
      s1 += __shfl_xor(s1, 32); s2 += __shfl_xor(s2, 32);
      mu = s1 * (1.f / 96.f);
      rs = rsqrtf(s2 * (1.f / 96.f) - mu * mu + 1e-5f);
    }
    bf16x8 afr[3];
#pragma unroll
    for (int ks = 0; ks < 3; ++ks)
#pragma unroll
      for (int e = 0; e < 8; ++e)
        afr[ks][e] = (short)f2bf((xv[ks * 8 + e] - mu) * rs * gl[ks * 8 + e] + bl[ks * 8 + e]);

    // ---- QKV GEMM: B-frags from LDS tiles ----
#pragma unroll
    for (int nt = 0; nt < 18; ++nt) {
      f32x4 acc = zz;
#pragma unroll
      for (int ks = 0; ks < 3; ++ks)
        acc = MFMA(afr[ks],
                   *reinterpret_cast<const bf16x8*>(&WqkvL[((nt * 3 + ks) << 9) + (l16 << 5) + lg * 8]),
                   acc);
      float bc = qb[nt];
      if (nt < 6) {
#pragma unroll
        for (int j = 0; j < 4; ++j)
          R1[(wvg * 16 + lg * 4 + j) * 104 + nt * 16 + l16] = f2bf((acc[j] + bc) * qscale);
      } else if (nt < 12) {
#pragma unroll
        for (int j = 0; j < 4; ++j)
          Ks[(wvg * 16 + lg * 4 + j) * 104 + (nt - 6) * 16 + l16] = f2bf(acc[j] + bc);
      } else {
#pragma unroll
        for (int j = 0; j < 4; ++j)
          Vt[((nt - 12) * 16 + l16) * 72 + wvg * 16 + lg * 4 + j] = f2bf(acc[j] + bc);
      }
    }
    __syncthreads();   // barrier 1: Ks/Vt visible to group

    // ---- prefetch next window's X (hidden under attention) ----
    int wn = w + 2;
    if (wn > 8191) wn = w;
    unsigned short* xfpn = xaddr(wn);
#pragma unroll
    for (int ks = 0; ks < 3; ++ks)
      xn[ks] = *reinterpret_cast<const bf16x8*>(&xfpn[ks * 32]);

    // ---- attention ----
    bf16x8 aqh[3];
#pragma unroll
    for (int h = 0; h < 3; ++h)
      aqh[h] = *reinterpret_cast<const bf16x8*>(&R1[arow * 104 + h * 32 + lg * 8]);

    f32x4 oacc[6];
#pragma unroll
    for (int i = 0; i < 6; ++i) oacc[i] = zz;

#pragma unroll 1
    for (int h = 0; h < 3; ++h) {
      f32x4 sc[4];
#pragma unroll
      for (int kt = 0; kt < 4; ++kt) {
        bf16x8 bk = *reinterpret_cast<const bf16x8*>(&Ks[(kt * 16 + l16) * 104 + h * 32 + lg * 8]);
        sc[kt] = MFMA(aqh[h], bk, zz);
      }
#pragma unroll
      for (int j = 0; j < 4; ++j) {
        int qi = wvg * 16 + lg * 4 + j;
        float e0 = __expf(sc[0][j] + bias_r[j][0]);
        float e1 = __expf(sc[1][j] + bias_r[j][1]);
        float e2 = __expf(sc[2][j] + bias_r[j][2]);
        float e3 = __expf(sc[3][j] + bias_r[j][3]);
        float s = e0 + e1 + e2 + e3;
#pragma unroll
        for (int off = 1; off < 16; off <<= 1) s += __shfl_xor(s, off);
        float inv = 1.0f / s;
        R1[qi * 104 +  0 + l16] = f2bf(e0 * inv);
        R1[qi * 104 + 16 + l16] = f2bf(e1 * inv);
        R1[qi * 104 + 32 + l16] = f2bf(e2 * inv);
        R1[qi * 104 + 48 + l16] = f2bf(e3 * inv);
      }
      bf16x8 ap0 = *reinterpret_cast<const bf16x8*>(&R1[arow * 104 +  0 + lg * 8]);
      bf16x8 ap1 = *reinterpret_cast<const bf16x8*>(&R1[arow * 104 + 32 + lg * 8]);
#pragma unroll
      for (int dt = 0; dt < 2; ++dt) {
        int vcol = h * 32 + dt * 16 + l16;
        bf16x8 bv0 = *reinterpret_cast<const bf16x8*>(&Vt[vcol * 72 +  0 + lg * 8]);
        bf16x8 bv1 = *reinterpret_cast<const bf16x8*>(&Vt[vcol * 72 + 32 + lg * 8]);
        oacc[h * 2 + dt] = MFMA(ap0, bv0, oacc[h * 2 + dt]);
        oacc[h * 2 + dt] = MFMA(ap1, bv1, oacc[h * 2 + dt]);
      }
    }
    __syncthreads();   // barrier 2: Ks/Vt reads done; next iter may overwrite

    // ---- O -> R1 (band-private) ----
#pragma unroll
    for (int i = 0; i < 6; ++i)
#pragma unroll
      for (int j = 0; j < 4; ++j)
        R1[(wvg * 16 + lg * 4 + j) * 104 + i * 16 + l16] = f2bf(oacc[i][j]);

    // ---- proj (B-frags from LDS) -> R1 band ----
    bf16x8 ao[3];
#pragma unroll
    for (int ks = 0; ks < 3; ++ks)
      ao[ks] = *reinterpret_cast<const bf16x8*>(&R1[arow * 104 + ks * 32 + lg * 8]);
#pragma unroll
    for (int nt = 0; nt < 6; ++nt) {
      f32x4 acc = zz;
#pragma unroll
      for (int ks = 0; ks < 3; ++ks)
        acc = MFMA(ao[ks],
                   *reinterpret_cast<const bf16x8*>(&WprojL[((nt * 3 + ks) << 9) + (l16 << 5) + lg * 8]),
                   acc);
      float pb = pbr[nt];
#pragma unroll
      for (int j = 0; j < 4; ++j)
        R1[(wvg * 16 + lg * 4 + j) * 104 + nt * 16 + l16] = f2bf(acc[j] + pb);
    }
    // ---- epilogue in frag layout: own band row + xv residual -> X ----
#pragma unroll
    for (int ks = 0; ks < 3; ++ks) {
      bf16x8 m = *reinterpret_cast<const bf16x8*>(&R1[ftok * 104 + ks * 32 + lg * 8]);
      bf16x8 pk;
#pragma unroll
      for (int e = 0; e < 8; ++e)
        pk[e] = (short)f2bf(bf2f((unsigned short)m[e]) + xv[ks * 8 + e]);
      *reinterpret_cast<bf16x8*>(&xfp[ks * 32]) = pk;
    }
    xfp = xfpn;
    w = wn;
  }
}

// ---------------------------------------------------------------------------
// Kernel 2: weight-stationary MLP (unchanged from R8/R9 best).
// ---------------------------------------------------------------------------
__global__ __launch_bounds__(512, 2) void k_mlp(
    const unsigned short* __restrict__ X,
    const float* __restrict__ ln2g, const float* __restrict__ ln2b,
    const unsigned short* __restrict__ w1p,
    const float* __restrict__ b1,
    const unsigned short* __restrict__ w2p,
    const float* __restrict__ b2,
    float* __restrict__ out)
{
  __shared__ __align__(16) unsigned short Wl[36864];
  __shared__ __align__(16) unsigned short W2l[34816];
  __shared__ __align__(16) unsigned short Hl[128 * 72];

  const int tid = threadIdx.x;
  const int q    = tid & 3;
  const int t    = tid >> 2;
  const int lane = tid & 63;
  const int wv   = tid >> 6;
  const int l16  = lane & 15;
  const int lg   = lane >> 4;
  const f32x4 zz = {0.f, 0.f, 0.f, 0.f};

#pragma unroll
  for (int it = 0; it < 9; ++it) {
    int v8 = it * 512 + tid;
    *reinterpret_cast<bf16x8*>(&Wl[v8 * 8]) = *reinterpret_cast<const bf16x8*>(&w1p[v8 * 8]);
    if (v8 < 4352)
      *reinterpret_cast<bf16x8*>(&W2l[v8 * 8]) = *reinterpret_cast<const bf16x8*>(&w2p[v8 * 8]);
  }
  bf16x8 wfr[4];
#pragma unroll
  for (int r = 0; r < 4; ++r)
    wfr[r] = *reinterpret_cast<const bf16x8*>(&w2p[((68 + r) << 9) + (l16 << 5) + lg * 8]);

  float gr[24], br[24], b1r[24], b2r[6];
#pragma unroll
  for (int i = 0; i < 24; ++i) {
    int c = (i >> 3) * 32 + lg * 8 + (i & 7);
    gr[i] = ln2g[c]; br[i] = ln2b[c];
  }
#pragma unroll
  for (int i = 0; i < 24; ++i) b1r[i] = b1[i * 16 + l16];
#pragma unroll
  for (int i = 0; i < 6; ++i) b2r[i] = b2[i * 16 + l16];

  __syncthreads();

#pragma unroll 1
  for (int s = 0; s < 8; ++s) {
    const int stb = (blockIdx.x * 8 + s) * 128;

    const unsigned short* xfp = &X[(size_t)(stb + wv * 16 + l16) * 96 + lg * 8];
    float xv[24];
#pragma unroll
    for (int ks = 0; ks < 3; ++ks) {
      bf16x8 g2 = *reinterpret_cast<const bf16x8*>(&xfp[ks * 32]);
#pragma unroll
      for (int e = 0; e < 8; ++e) xv[ks * 8 + e] = bf2f((unsigned short)g2[e]);
    }
    float mu, rs;
    {
      float s1 = 0.f, s2 = 0.f;
#pragma unroll
      for (int k = 0; k < 24; ++k) { float v = xv[k]; s1 += v; s2 += v * v; }
      s1 += __shfl_xor(s1, 16); s2 += __shfl_xor(s2, 16);
      s1 += __shfl_xor(s1, 32); s2 += __shfl_xor(s2, 32);
      mu = s1 * (1.f / 96.f);
      rs = rsqrtf(s2 * (1.f / 96.f) - mu * mu + 1e-5f);
    }
    bf16x8 a1[3];
#pragma unroll
    for (int ks = 0; ks < 3; ++ks)
#pragma unroll
      for (int e = 0; e < 8; ++e)
        a1[ks][e] = (short)f2bf((xv[ks * 8 + e] - mu) * rs * gr[ks * 8 + e] + br[ks * 8 + e]);

    f32x4 acc2[6];
#pragma unroll
    for (int i = 0; i < 6; ++i) acc2[i] = zz;

#pragma unroll
    for (int ch = 0; ch < 6; ++ch) {
#pragma unroll
      for (int nt = 0; nt < 4; ++nt) {
        const int ntg = ch * 4 + nt;
        f32x4 acc = zz;
#pragma unroll
        for (int ks = 0; ks < 3; ++ks)
          acc = MFMA(a1[ks],
                     *reinterpret_cast<const bf16x8*>(&Wl[((ntg * 3 + ks) << 9) + (l16 << 5) + lg * 8]),
                     acc);
        float bb = b1r[ntg];
#pragma unroll
        for (int j = 0; j < 4; ++j) {
          float v = acc[j] + bb;
          float tt = v * fmaf(0.071354816f, v * v, 1.5957691f);
          float gg = v * __builtin_amdgcn_rcpf(1.f + __expf(-tt));
          Hl[(wv * 16 + lg * 4 + j) * 72 + nt * 16 + l16] = f2bf(gg);
        }
      }
      bf16x8 ah0 = *reinterpret_cast<const bf16x8*>(&Hl[(wv * 16 + l16) * 72 + lg * 8]);
      bf16x8 ah1 = *reinterpret_cast<const bf16x8*>(&Hl[(wv * 16 + l16) * 72 + 32 + lg * 8]);
#pragma unroll
      for (int nt = 0; nt < 6; ++nt) {
        const int t0 = nt * 12 + ch * 2;
        const int t1 = t0 + 1;
        bf16x8 bf0 = (t0 >= 68) ? wfr[(t0 - 68) & 3]
                   : *reinterpret_cast<const bf16x8*>(&W2l[(t0 << 9) + (l16 << 5) + lg * 8]);
        bf16x8 bf1 = (t1 >= 68) ? wfr[(t1 - 68) & 3]
                   : *reinterpret_cast<const bf16x8*>(&W2l[(t1 << 9) + (l16 << 5) + lg * 8]);
        acc2[nt] = MFMA(ah0, bf0, acc2[nt]);
        acc2[nt] = MFMA(ah1, bf1, acc2[nt]);
      }
    }

    const int tok = stb + t;
    const unsigned short* xrp = &X[(size_t)tok * 96 + q * 24];
    const int bb_ = tok >> 18;
    const int pix = tok & 262143;
#pragma unroll
    for (int pass = 0; pass < 2; ++pass) {
#pragma unroll
      for (int ntl = 0; ntl < 3; ++ntl) {
        const int nt = pass * 3 + ntl;
#pragma unroll
        for (int j = 0; j < 4; ++j)
          Hl[(wv * 16 + lg * 4 + j) * 72 + ntl * 16 + l16] = f2bf(acc2[nt][j] + b2r[nt]);
      }
      if ((q >> 1) == pass) {
        const int lc = (q & 1) * 24;
#pragma unroll
        for (int v = 0; v < 3; ++v) {
          bf16x8 m  = *reinterpret_cast<const bf16x8*>(&Hl[t * 72 + lc + v * 8]);
          bf16x8 xr = *reinterpret_cast<const bf16x8*>(&xrp[v * 8]);
#pragma unroll
          for (int e = 0; e < 8; ++e) {
            int c = q * 24 + v * 8 + e;
            out[((size_t)(bb_ * 96 + c) << 18) + pix] =
                bf2f((unsigned short)m[e]) + bf2f((unsigned short)xr[e]);
          }
        }
      }
    }
  }
}

// ---------------------------------------------------------------------------
extern "C" void kernel_launch(void* const* d_in, const int* in_sizes, int n_in,
                              void* d_out, int out_size, void* d_ws, size_t ws_size,
                              hipStream_t stream) {
  const float* x     = (const float*)d_in[0];
  const float* ln1g  = (const float*)d_in[1];
  const float* ln1b  = (const float*)d_in[2];
  const float* qkv_w = (const float*)d_in[3];
  const float* qkv_b = (const float*)d_in[4];
  const float* lapA  = (const float*)d_in[5];
  const float* lapB  = (const float*)d_in[6];
  const float* prj_w = (const float*)d_in[7];
  const float* prj_b = (const float*)d_in[8];
  const float* ln2g  = (const float*)d_in[9];
  const float* ln2b  = (const float*)d_in[10];
  const float* w1f   = (const float*)d_in[11];
  const float* b1    = (const float*)d_in[12];
  const float* w2f   = (const float*)d_in[13];
  const float* b2    = (const float*)d_in[14];

  char* ws = (char*)d_ws;
  unsigned short* X     = (unsigned short*)ws;                 // bf16 [524288][96]
  unsigned short* qkvwp = (unsigned short*)(ws + 100663296);   // permuted tiles
  unsigned short* prjwp = (unsigned short*)(ws + 100718592);   // permuted tiles
  unsigned short* w1p   = (unsigned short*)(ws + 100737024);   // permuted tiles
  unsigned short* w2p   = (unsigned short*)(ws + 100810752);   // permuted tiles

  k_cvt_pt<<<108, 256, 0, stream>>>(qkv_w, qkvwp, 288 * 96);
  k_cvt_pt<<<36,  256, 0, stream>>>(prj_w, prjwp, 96 * 96);
  k_cvt_pt<<<144, 256, 0, stream>>>(w1f,   w1p,   384 * 96);
  k_cvt_p2<<<144, 256, 0, stream>>>(w2f, w2p);

  k_pre <<<8192, 256, 0, stream>>>(x, X);
  k_attn<<<256, 512, 0, stream>>>(ln1g, ln1b, qkvwp, qkv_b, lapA, lapB,
                                  prjwp, prj_b, X);
  k_mlp <<<512, 512, 0, stream>>>(X, ln2g, ln2b, w1p, b1, w2p, b2,
                                  (float*)d_out);
}